// Round 10
// baseline (251.635 us; speedup 1.0000x reference)
//
#include <hip/hip_runtime.h>

#define D 64
#define BSH2 6                // 64 nodes per fused tile
#define BN2 (1 << BSH2)
#define RSH 9                 // 512 nodes per scatter region (8 tiles)
#define RN (1 << RSH)
#define NR_MAX 256            // supports N up to 131072
#define RCAPSH 14             // 16384-record capacity per region (mean 8192, +90 sigma)
#define RCAP (1 << RCAPSH)
#define SPR_MAX 2048          // per-tile record stage (mean 1024, +32 sigma)
#define SIDX_MAX (SPR_MAX + 3 * BN2)   // sorted-index LDS incl. per-node 4-align padding

typedef __attribute__((ext_vector_type(8))) short bf16x8;
typedef __attribute__((ext_vector_type(4))) float f32x4;

// ---------- bf16 helpers (bit-exact RNE pack, shift-based unpack) ----------
__device__ __forceinline__ unsigned int f2bf_rne(float f) {
    unsigned int b = __float_as_uint(f);
    return (b + 0x7fffu + ((b >> 16) & 1u)) >> 16;
}
__device__ __forceinline__ unsigned int pack_bf(float lo, float hi) {
    return f2bf_rne(lo) | (f2bf_rne(hi) << 16);
}
__device__ __forceinline__ float bflo(unsigned int u) { return __uint_as_float(u << 16); }
__device__ __forceinline__ float bfhi(unsigned int u) { return __uint_as_float(u & 0xffff0000u); }

// ---------- cast fp32 features -> packed bf16 (2 feats per uint); also zeroes cnt ----------
__global__ void cast_kernel(const float4* __restrict__ xin, uint2* __restrict__ xb, int n4,
                            int* __restrict__ cnt, int nz) {
    int gid = blockIdx.x * blockDim.x + threadIdx.x;
    if (gid < nz) cnt[gid] = 0;
    int stride = gridDim.x * blockDim.x;
    for (int i = gid; i < n4; i += stride) {
        float4 v = xin[i];
        uint2 o;
        o.x = pack_bf(v.x, v.y);
        o.y = pack_bf(v.z, v.w);
        xb[i] = o;
    }
}

// ---------- single-pass region scatter: (src | dst_low9<<17) into RCAP-strided regions ----------
// Region = 512 dst nodes. R9's 64-node buckets gave 2-record runs per (block,bucket):
// 48MB HBM writes for 6.4MB of records (multi-XCD 4B-per-line dirtying) + 690K global
// reservation atomics. 196 regions -> 16-record (64B) single-writer runs, 100K atomics.
__global__ __launch_bounds__(256) void binscatter_kernel(
    const int* __restrict__ src, const int* __restrict__ dst,
    int* __restrict__ cnt, unsigned int* __restrict__ pairs,
    int E, int NR, int CE) {
    __shared__ int lh[NR_MAX];
    __shared__ int lbase[NR_MAX];
    for (int k = threadIdx.x; k < NR; k += 256) lh[k] = 0;
    __syncthreads();
    int b = blockIdx.x;
    int beg = b * CE, end = min(beg + CE, E);
    for (int e = beg + threadIdx.x; e < end; e += 256)
        atomicAdd(&lh[dst[e] >> RSH], 1);
    __syncthreads();
    for (int k = threadIdx.x; k < NR; k += 256) {
        int c = lh[k];
        if (c) lbase[k] = (k << RCAPSH) + atomicAdd(&cnt[k], c);
        lh[k] = 0;
    }
    __syncthreads();
    for (int e = beg + threadIdx.x; e < end; e += 256) {
        int d = dst[e];
        int k = d >> RSH;
        int r = atomicAdd(&lh[k], 1);
        pairs[lbase[k] + r] = (unsigned int)src[e] | ((unsigned int)(d & (RN - 1)) << 17);
    }
}

// ---------- fused layer: region-filter + in-LDS counting sort + gather-mean + MFMA ----------
// One block (256 thr = 4 waves) per 64-node tile. Grid maps region == blockIdx (mod 8):
// all 8 sub-tiles of a region land on the SAME XCD (round-robin dispatch), so the ~33KB
// region stream is fetched into that XCD's L2 once and hit 7 more times.
// Phase A: stream region records, keep (rec>>23)&7 == sub, compact into spr, 64-counter
// hist, padded scan (4-aligned bases), LDS scatter -> per-node lists in sidx.
// Phase B: proven register gather (8 lanes x uint4/row, 4-deep unroll, index int4 from
// LDS). Means -> swizzled bf16 LDS tile (overlays dead record stage).
// Phase C: 16x16x32 MFMA with hi/lo-split weights (fp32-accurate).
__global__ __launch_bounds__(256) void fused_layer_kernel(
    const unsigned int* __restrict__ xin, const unsigned int* __restrict__ pairs,
    const int* __restrict__ cnt,
    const float* __restrict__ Wl, const float* __restrict__ Wr,
    const float* __restrict__ bias,
    float* __restrict__ outf, unsigned int* __restrict__ outb,
    int N, int NR, int relu) {
    __shared__ uint4 smean[BN2][8];     // 8KB; overlaid as the record stage in phase A
    __shared__ int sidx[SIDX_MAX];      // sorted src indices, per-node 4-aligned lists
    __shared__ int lcnt[BN2];           // true degree
    __shared__ int lbase[BN2];          // 4-aligned list base
    __shared__ int lcur[BN2];           // scatter cursor
    __shared__ int sscan[BN2];
    __shared__ int scnt0;

    unsigned int* spr = (unsigned int*)&smean[0][0];   // phase-A overlay (2048 uints)

    int x = blockIdx.x & 7;
    int j = blockIdx.x >> 3;
    int region = ((j >> 3) << 3) | x;   // region % 8 == blockIdx % 8 -> same XCD
    int sub = j & 7;
    if (region >= NR) return;
    int node0 = (region << RSH) + (sub << BSH2);
    if (node0 >= N) return;

    int tid = threadIdx.x;
    int wave = tid >> 6;
    int lane = tid & 63;

    // ---- phase A: stream region, filter this tile's records, counting sort in LDS ----
    if (tid == 0) scnt0 = 0;
    if (tid < BN2) lcnt[tid] = 0;
    __syncthreads();
    int cR = min(cnt[region], RCAP);
    int rb = region << RCAPSH;
    for (int i = tid; i < cR; i += 256) {
        unsigned int rec = pairs[rb + i];
        if (((rec >> 23) & 7u) == (unsigned int)sub) {
            int p = atomicAdd(&scnt0, 1);
            if (p < SPR_MAX) {
                spr[p] = rec;
                atomicAdd(&lcnt[(rec >> 17) & (BN2 - 1)], 1);
            }
        }
    }
    __syncthreads();
    int cntk = min(scnt0, SPR_MAX);
    int deg = (tid < BN2) ? lcnt[tid] : 0;
    int ps  = (deg + 3) & ~3;           // pad each node's list to 4-record alignment
    if (tid < BN2) sscan[tid] = ps;
    __syncthreads();
    for (int off = 1; off < BN2; off <<= 1) {
        int t = (tid < BN2 && tid >= off) ? sscan[tid - off] : 0;
        __syncthreads();
        if (tid < BN2) sscan[tid] += t;
        __syncthreads();
    }
    if (tid < BN2) {
        int base = sscan[tid] - ps;     // exclusive prefix of padded degrees, 4-aligned
        lbase[tid] = base;
        lcur[tid] = base;
    }
    __syncthreads();
    for (int i = tid; i < cntk; i += 256) {
        unsigned int rec = spr[i];
        int jn = (rec >> 17) & (BN2 - 1);
        int pos = atomicAdd(&lcur[jn], 1);
        sidx[pos] = (int)(rec & 0x1FFFFu);
    }
    __syncthreads();                    // spr dead from here; smean reuses the space

    // ---- phase B: aggregation (register accumulation, indices from LDS) ----
    int q  = lane >> 3;                 // node within octet
    int fl = lane & 7;                  // uint4 granule within 128B row
    for (int o = 0; o < 2; ++o) {
        int nl = (wave << 4) + (o << 3) + q;      // local node 0..63
        int beg = lbase[nl];
        int dg  = lcnt[nl];
        int end = beg + dg;
        float s0 = 0.f, s1 = 0.f, s2 = 0.f, s3 = 0.f;
        float s4 = 0.f, s5 = 0.f, s6 = 0.f, s7 = 0.f;
        int jj = beg;
        for (; jj + 4 <= end; jj += 4) {
            int4 iv = *(const int4*)(sidx + jj);  // 16B-aligned ds_read_b128
            uint4 u0 = *(const uint4*)(xin + iv.x * 32 + fl * 4);
            uint4 u1 = *(const uint4*)(xin + iv.y * 32 + fl * 4);
            uint4 u2 = *(const uint4*)(xin + iv.z * 32 + fl * 4);
            uint4 u3 = *(const uint4*)(xin + iv.w * 32 + fl * 4);
            s0 += bflo(u0.x) + bflo(u1.x) + bflo(u2.x) + bflo(u3.x);
            s1 += bfhi(u0.x) + bfhi(u1.x) + bfhi(u2.x) + bfhi(u3.x);
            s2 += bflo(u0.y) + bflo(u1.y) + bflo(u2.y) + bflo(u3.y);
            s3 += bfhi(u0.y) + bfhi(u1.y) + bfhi(u2.y) + bfhi(u3.y);
            s4 += bflo(u0.z) + bflo(u1.z) + bflo(u2.z) + bflo(u3.z);
            s5 += bfhi(u0.z) + bfhi(u1.z) + bfhi(u2.z) + bfhi(u3.z);
            s6 += bflo(u0.w) + bflo(u1.w) + bflo(u2.w) + bflo(u3.w);
            s7 += bfhi(u0.w) + bfhi(u1.w) + bfhi(u2.w) + bfhi(u3.w);
        }
        for (; jj < end; ++jj) {
            uint4 u = *(const uint4*)(xin + sidx[jj] * 32 + fl * 4);
            s0 += bflo(u.x); s1 += bfhi(u.x);
            s2 += bflo(u.y); s3 += bfhi(u.y);
            s4 += bflo(u.z); s5 += bfhi(u.z);
            s6 += bflo(u.w); s7 += bfhi(u.w);
        }
        float inv = 1.0f / fmaxf((float)dg, 1.0f);
        uint4 ov;
        ov.x = pack_bf(s0 * inv, s1 * inv);
        ov.y = pack_bf(s2 * inv, s3 * inv);
        ov.z = pack_bf(s4 * inv, s5 * inv);
        ov.w = pack_bf(s6 * inv, s7 * inv);
        smean[nl][fl ^ (nl & 7)] = ov;   // zero-degree nodes write zeros (dg=0 -> sums 0)
    }

    // ---- weight fragments (overlap load latency with barrier wait) ----
    int lm   = lane & 15;
    int quad = lane >> 4;
    int f_a  = (wave << 4) + lm;
    bf16x8 wh[4], wlo[4];
#pragma unroll
    for (int s = 0; s < 4; ++s) {
        int k8 = s * 32 + quad * 8;
        const float* Wsrc = (k8 < 64) ? Wl : Wr;
        const float* p = Wsrc + f_a * 64 + (k8 & 63);
        float4 w0 = *(const float4*)p;
        float4 w1 = *(const float4*)(p + 4);
        float w[8] = {w0.x, w0.y, w0.z, w0.w, w1.x, w1.y, w1.z, w1.w};
        bf16x8 h, l;
#pragma unroll
        for (int jj = 0; jj < 8; ++jj) {
            unsigned int hb = f2bf_rne(w[jj]);
            float hf = __uint_as_float(hb << 16);
            unsigned int lb = f2bf_rne(w[jj] - hf);
            h[jj] = (short)hb;
            l[jj] = (short)lb;
        }
        wh[s] = h;
        wlo[s] = l;
    }

    __syncthreads();

    // ---- phase C: MFMA, out[f][node] tiles; K = [mean(64) ; x(64)] ----
    f32x4 acc[4];
#pragma unroll
    for (int nt = 0; nt < 4; ++nt) acc[nt] = (f32x4){0.f, 0.f, 0.f, 0.f};

#pragma unroll
    for (int nt = 0; nt < 4; ++nt) {
        int nl = nt * 16 + lm;
        int node = node0 + nl;
        bool v = node < N;
        const unsigned int* xrow = xin + (long long)node * 32;
#pragma unroll
        for (int s = 0; s < 2; ++s) {            // mean fragments from LDS
            union { uint4 u4; bf16x8 v8; } cv;
            cv.u4 = smean[nl][(s * 4 + quad) ^ (lm & 7)];
            acc[nt] = __builtin_amdgcn_mfma_f32_16x16x32_bf16(wh[s],  cv.v8, acc[nt], 0, 0, 0);
            acc[nt] = __builtin_amdgcn_mfma_f32_16x16x32_bf16(wlo[s], cv.v8, acc[nt], 0, 0, 0);
        }
#pragma unroll
        for (int s = 2; s < 4; ++s) {            // self fragments from global
            uint4 u = make_uint4(0u, 0u, 0u, 0u);
            if (v) u = *(const uint4*)(xrow + ((s & 1) << 4) + (quad << 2));
            union { uint4 u4; bf16x8 v8; } cv;
            cv.u4 = u;
            acc[nt] = __builtin_amdgcn_mfma_f32_16x16x32_bf16(wh[s],  cv.v8, acc[nt], 0, 0, 0);
            acc[nt] = __builtin_amdgcn_mfma_f32_16x16x32_bf16(wlo[s], cv.v8, acc[nt], 0, 0, 0);
        }
    }

    int fb = (wave << 4) + quad * 4;
    float4 bv = *(const float4*)(bias + fb);
#pragma unroll
    for (int nt = 0; nt < 4; ++nt) {
        int node = node0 + nt * 16 + lm;
        if (node >= N) continue;
        float r0 = acc[nt][0] + bv.x;
        float r1 = acc[nt][1] + bv.y;
        float r2 = acc[nt][2] + bv.z;
        float r3 = acc[nt][3] + bv.w;
        if (relu) {
            r0 = fmaxf(r0, 0.f); r1 = fmaxf(r1, 0.f);
            r2 = fmaxf(r2, 0.f); r3 = fmaxf(r3, 0.f);
        }
        if (outf) *(float4*)(outf + (long long)node * D + fb) = make_float4(r0, r1, r2, r3);
        if (outb) *(uint2*)(outb + (long long)node * 32 + (fb >> 1)) =
                      make_uint2(pack_bf(r0, r1), pack_bf(r2, r3));
    }
}

extern "C" void kernel_launch(void* const* d_in, const int* in_sizes, int n_in,
                              void* d_out, int out_size, void* d_ws, size_t ws_size,
                              hipStream_t stream) {
    const float* x   = (const float*)d_in[0];
    const int* ei    = (const int*)d_in[1];
    const float* W1l = (const float*)d_in[2];
    const float* W1r = (const float*)d_in[3];
    const float* b1  = (const float*)d_in[4];
    const float* W2l = (const float*)d_in[5];
    const float* W2r = (const float*)d_in[6];
    const float* b2  = (const float*)d_in[7];

    const int E = in_sizes[1] / 2;
    const int N = in_sizes[0] / D;     // requires N <= 131072 (17-bit packing)
    const int* src  = ei;
    const int* dstp = ei + E;
    const int NR = (N + RN - 1) >> RSH;           // 196 for N=100k
    const int G1 = 512;                           // latency hiding for the scatter
    const int CE = (E + G1 - 1) / G1;
    const int G2 = 64 * ((NR + 7) >> 3);          // 8 XCD slots x 8 subs x region slots

    char* ws = (char*)d_ws;
    size_t off = 0;
    auto alloc = [&](size_t bytes) { void* p = ws + off; off = (off + bytes + 255) & ~(size_t)255; return p; };
    int* cnt            = (int*)alloc((size_t)NR * 4);
    unsigned int* pairs = (unsigned int*)alloc(((size_t)(NR + 1) << RCAPSH) * 4);
    unsigned int* xb    = (unsigned int*)alloc((size_t)N * 32 * 4);  // bf16 x
    unsigned int* hb    = (unsigned int*)alloc((size_t)N * 32 * 4);  // bf16 h

    float* out = (float*)d_out;

    // ---- cast features to bf16 (+ zero region counters) ----
    cast_kernel<<<2048, 256, 0, stream>>>((const float4*)x, (uint2*)xb, N * 16, cnt, NR);

    // ---- single-pass 512-node-region scatter (fine sort happens inside the fused layer) ----
    binscatter_kernel<<<G1, 256, 0, stream>>>(src, dstp, cnt, pairs, E, NR, CE);

    // ---- layer 1: filter + sort + gather-mean + MFMA linear -> bf16 h ----
    fused_layer_kernel<<<G2, 256, 0, stream>>>(xb, pairs, cnt, W1l, W1r, b1,
                                               nullptr, hb, N, NR, 1);
    // ---- layer 2: filter + sort + gather-mean + MFMA linear -> fp32 out ----
    fused_layer_kernel<<<G2, 256, 0, stream>>>(hb, pairs, cnt, W2l, W2r, b2,
                                               out, nullptr, N, NR, 0);
}

// Round 11
// 233.528 us; speedup vs baseline: 1.0775x; 1.0775x over previous
//
#include <hip/hip_runtime.h>

#define D 64
#define BSH2 6                // 64 nodes per fused tile / fine bucket
#define BN2 (1 << BSH2)
#define RSH 9                 // 512 nodes per coarse scatter region (8 fine buckets)
#define RN (1 << RSH)
#define NR_MAX 256            // supports N up to 131072
#define RCAPSH 14             // 16384-record capacity per coarse region (mean 8192)
#define RCAP (1 << RCAPSH)
#define RSTAGE 12288          // rebin LDS sorted stage cap (mean 8192, +45 sigma)
#define FCAPSH 11             // 2048-record capacity per fine bucket (mean 1024, +32 sigma)
#define FCAP (1 << FCAPSH)
#define SPR_MAX FCAP          // fused per-tile record stage
#define SIDX_MAX (SPR_MAX + 3 * BN2)   // sorted-index LDS incl. per-node 4-align padding

typedef __attribute__((ext_vector_type(8))) short bf16x8;
typedef __attribute__((ext_vector_type(4))) float f32x4;

// ---------- bf16 helpers (bit-exact RNE pack, shift-based unpack) ----------
__device__ __forceinline__ unsigned int f2bf_rne(float f) {
    unsigned int b = __float_as_uint(f);
    return (b + 0x7fffu + ((b >> 16) & 1u)) >> 16;
}
__device__ __forceinline__ unsigned int pack_bf(float lo, float hi) {
    return f2bf_rne(lo) | (f2bf_rne(hi) << 16);
}
__device__ __forceinline__ float bflo(unsigned int u) { return __uint_as_float(u << 16); }
__device__ __forceinline__ float bfhi(unsigned int u) { return __uint_as_float(u & 0xffff0000u); }

// ---------- cast fp32 features -> packed bf16 (2 feats per uint); also zeroes cnt ----------
__global__ void cast_kernel(const float4* __restrict__ xin, uint2* __restrict__ xb, int n4,
                            int* __restrict__ cnt, int nz) {
    int gid = blockIdx.x * blockDim.x + threadIdx.x;
    if (gid < nz) cnt[gid] = 0;
    int stride = gridDim.x * blockDim.x;
    for (int i = gid; i < n4; i += stride) {
        float4 v = xin[i];
        uint2 o;
        o.x = pack_bf(v.x, v.y);
        o.y = pack_bf(v.z, v.w);
        xb[i] = o;
    }
}

// ---------- level 1: coarse scatter (src | dst_low9<<17) into 196 RCAP-strided regions ----------
// 196-way fan-out from 512 blocks -> ~16-record (64B) single-writer runs, ~100K global
// reservation atomics. (R9's direct 1563-way fan-out gave 2-record runs: 48MB HBM writes
// for 6.4MB of records. R10's consumer-side filter cost +21us/layer. Two-level wins.)
__global__ __launch_bounds__(256) void binscatter_kernel(
    const int* __restrict__ src, const int* __restrict__ dst,
    int* __restrict__ cnt, unsigned int* __restrict__ pairs,
    int E, int NR, int CE) {
    __shared__ int lh[NR_MAX];
    __shared__ int lbase[NR_MAX];
    for (int k = threadIdx.x; k < NR; k += 256) lh[k] = 0;
    __syncthreads();
    int b = blockIdx.x;
    int beg = b * CE, end = min(beg + CE, E);
    for (int e = beg + threadIdx.x; e < end; e += 256)
        atomicAdd(&lh[dst[e] >> RSH], 1);
    __syncthreads();
    for (int k = threadIdx.x; k < NR; k += 256) {
        int c = lh[k];
        if (c) lbase[k] = (k << RCAPSH) + atomicAdd(&cnt[k], c);
        lh[k] = 0;
    }
    __syncthreads();
    for (int e = beg + threadIdx.x; e < end; e += 256) {
        int d = dst[e];
        int k = d >> RSH;
        int r = atomicAdd(&lh[k], 1);
        pairs[lbase[k] + r] = (unsigned int)src[e] | ((unsigned int)(d & (RN - 1)) << 17);
    }
}

// ---------- level 2: rebin each region 8-way into fine 64-node buckets ----------
// One block per region. Pass 1: private 8-bin counts (no atomics) -> 2048-wide block
// scan (s-major, t-minor) -> per-thread running offsets. Pass 2: re-read region (L2-hot),
// LDS-scatter into sorted stage. Copy-out: per-sub dense coalesced writes to pairs2
// (fine bucket stride FCAP) + exact cnt2. All global writes coalesced; zero atomics.
__global__ __launch_bounds__(256) void rebin_kernel(
    const unsigned int* __restrict__ pairs, const int* __restrict__ cnt,
    unsigned int* __restrict__ pairs2, int* __restrict__ cnt2, int NR) {
    __shared__ unsigned int srt[RSTAGE];   // 48KB sorted stage
    __shared__ int cm[2048];               // counts / exclusive offsets, idx = s*256 + t
    __shared__ int sblk[256];
    __shared__ int sbase[9];
    int r = blockIdx.x;
    int tid = threadIdx.x;
    int cR = min(cnt[r], RSTAGE);
    int rb = r << RCAPSH;

    int myc[8] = {0, 0, 0, 0, 0, 0, 0, 0};
    for (int i = tid; i < cR; i += 256)
        myc[(pairs[rb + i] >> 23) & 7u]++;
#pragma unroll
    for (int s = 0; s < 8; ++s) cm[s * 256 + tid] = myc[s];
    __syncthreads();
    // exclusive scan of cm[0..2048), 8 contiguous elements per thread
    int loc[8];
    int sum = 0;
#pragma unroll
    for (int k = 0; k < 8; ++k) { int v = cm[tid * 8 + k]; loc[k] = sum; sum += v; }
    sblk[tid] = sum;
    __syncthreads();
    for (int off = 1; off < 256; off <<= 1) {
        int t = (tid >= off) ? sblk[tid - off] : 0;
        __syncthreads();
        sblk[tid] += t;
        __syncthreads();
    }
    int ebase = sblk[tid] - sum;
#pragma unroll
    for (int k = 0; k < 8; ++k) cm[tid * 8 + k] = ebase + loc[k];
    __syncthreads();
    if (tid < 8) sbase[tid] = cm[tid * 256];
    if (tid == 0) sbase[8] = sblk[255];    // grand total
    int off8[8];
#pragma unroll
    for (int s = 0; s < 8; ++s) off8[s] = cm[s * 256 + tid];
    for (int i = tid; i < cR; i += 256) {  // same order as pass 1
        unsigned int rec = pairs[rb + i];
        int s = (rec >> 23) & 7u;
        srt[off8[s]++] = rec & 0x7FFFFFu;  // keep src17 | dst_low6<<17
    }
    __syncthreads();
#pragma unroll
    for (int s = 0; s < 8; ++s) {
        int cs = sbase[s];
        int n = min(sbase[s + 1] - cs, FCAP);
        unsigned int* dp = pairs2 + ((size_t)((r << 3) + s) << FCAPSH);
        for (int i = tid; i < n; i += 256) dp[i] = srt[cs + i];
        if (tid == 0) cnt2[(r << 3) + s] = n;
    }
}

// ---------- fused layer (R9 champion, verbatim): in-LDS sort + gather-mean + MFMA ----------
// One block (256 thr = 4 waves) per 64-node bucket. Phase A: stage this bucket's ~1024
// records into LDS (one coalesced read), 64-counter hist, padded scan (4-aligned bases),
// LDS scatter -> per-node contiguous index lists in sidx. Phase B: register gather
// (wave w: nodes [w*16,w*16+16) in two octets, 8 lanes x uint4/row, 4-deep unroll),
// index int4 via ds_read_b128. Means -> swizzled bf16 LDS tile (overlays dead stage).
// Phase C: 16x16x32 MFMA with hi/lo-split weights (fp32-accurate).
__global__ __launch_bounds__(256) void fused_layer_kernel(
    const unsigned int* __restrict__ xin, const unsigned int* __restrict__ pairs2,
    const int* __restrict__ cnt2,
    const float* __restrict__ Wl, const float* __restrict__ Wr,
    const float* __restrict__ bias,
    float* __restrict__ outf, unsigned int* __restrict__ outb, int N, int relu) {
    __shared__ uint4 smean[BN2][8];     // 8KB; overlaid as the record stage in phase A
    __shared__ int sidx[SIDX_MAX];      // sorted src indices, per-node 4-aligned lists
    __shared__ int lcnt[BN2];           // true degree
    __shared__ int lbase[BN2];          // 4-aligned list base
    __shared__ int lcur[BN2];           // scatter cursor
    __shared__ int sscan[BN2];

    unsigned int* spr = (unsigned int*)&smean[0][0];   // phase-A overlay (2048 uints)

    int tid = threadIdx.x;
    int wave = tid >> 6;
    int lane = tid & 63;
    int b = blockIdx.x;
    int node0 = b << BSH2;

    // ---- phase A: stage + counting sort in LDS ----
    int cntk = min(cnt2[b], SPR_MAX);
    if (tid < BN2) lcnt[tid] = 0;
    __syncthreads();
    long long rbeg = (long long)b << FCAPSH;
    for (int i = tid; i < cntk; i += 256) {
        unsigned int rec = pairs2[rbeg + i];
        spr[i] = rec;
        atomicAdd(&lcnt[(rec >> 17) & (BN2 - 1)], 1);
    }
    __syncthreads();
    int deg = (tid < BN2) ? lcnt[tid] : 0;
    int ps  = (deg + 3) & ~3;           // pad each node's list to 4-record alignment
    if (tid < BN2) sscan[tid] = ps;
    __syncthreads();
    for (int off = 1; off < BN2; off <<= 1) {
        int t = (tid < BN2 && tid >= off) ? sscan[tid - off] : 0;
        __syncthreads();
        if (tid < BN2) sscan[tid] += t;
        __syncthreads();
    }
    if (tid < BN2) {
        int base = sscan[tid] - ps;     // exclusive prefix of padded degrees, 4-aligned
        lbase[tid] = base;
        lcur[tid] = base;
    }
    __syncthreads();
    for (int i = tid; i < cntk; i += 256) {
        unsigned int rec = spr[i];
        int j = (rec >> 17) & (BN2 - 1);
        int pos = atomicAdd(&lcur[j], 1);
        sidx[pos] = (int)(rec & 0x1FFFFu);
    }
    __syncthreads();                    // spr dead from here; smean reuses the space

    // ---- phase B: aggregation (register accumulation, indices from LDS) ----
    int q  = lane >> 3;                 // node within octet
    int fl = lane & 7;                  // uint4 granule within 128B row
    for (int o = 0; o < 2; ++o) {
        int nl = (wave << 4) + (o << 3) + q;      // local node 0..63
        int beg = lbase[nl];
        int dg  = lcnt[nl];
        int end = beg + dg;
        float s0 = 0.f, s1 = 0.f, s2 = 0.f, s3 = 0.f;
        float s4 = 0.f, s5 = 0.f, s6 = 0.f, s7 = 0.f;
        int j = beg;
        for (; j + 4 <= end; j += 4) {
            int4 iv = *(const int4*)(sidx + j);   // 16B-aligned ds_read_b128
            uint4 u0 = *(const uint4*)(xin + iv.x * 32 + fl * 4);
            uint4 u1 = *(const uint4*)(xin + iv.y * 32 + fl * 4);
            uint4 u2 = *(const uint4*)(xin + iv.z * 32 + fl * 4);
            uint4 u3 = *(const uint4*)(xin + iv.w * 32 + fl * 4);
            s0 += bflo(u0.x) + bflo(u1.x) + bflo(u2.x) + bflo(u3.x);
            s1 += bfhi(u0.x) + bfhi(u1.x) + bfhi(u2.x) + bfhi(u3.x);
            s2 += bflo(u0.y) + bflo(u1.y) + bflo(u2.y) + bflo(u3.y);
            s3 += bfhi(u0.y) + bfhi(u1.y) + bfhi(u2.y) + bfhi(u3.y);
            s4 += bflo(u0.z) + bflo(u1.z) + bflo(u2.z) + bflo(u3.z);
            s5 += bfhi(u0.z) + bfhi(u1.z) + bfhi(u2.z) + bfhi(u3.z);
            s6 += bflo(u0.w) + bflo(u1.w) + bflo(u2.w) + bflo(u3.w);
            s7 += bfhi(u0.w) + bfhi(u1.w) + bfhi(u2.w) + bfhi(u3.w);
        }
        for (; j < end; ++j) {
            uint4 u = *(const uint4*)(xin + sidx[j] * 32 + fl * 4);
            s0 += bflo(u.x); s1 += bfhi(u.x);
            s2 += bflo(u.y); s3 += bfhi(u.y);
            s4 += bflo(u.z); s5 += bfhi(u.z);
            s6 += bflo(u.w); s7 += bfhi(u.w);
        }
        float inv = 1.0f / fmaxf((float)dg, 1.0f);
        uint4 ov;
        ov.x = pack_bf(s0 * inv, s1 * inv);
        ov.y = pack_bf(s2 * inv, s3 * inv);
        ov.z = pack_bf(s4 * inv, s5 * inv);
        ov.w = pack_bf(s6 * inv, s7 * inv);
        smean[nl][fl ^ (nl & 7)] = ov;   // zero-degree nodes write zeros (dg=0 -> sums 0)
    }

    // ---- weight fragments (overlap load latency with barrier wait) ----
    int lm   = lane & 15;
    int quad = lane >> 4;
    int f_a  = (wave << 4) + lm;
    bf16x8 wh[4], wlo[4];
#pragma unroll
    for (int s = 0; s < 4; ++s) {
        int k8 = s * 32 + quad * 8;
        const float* Wsrc = (k8 < 64) ? Wl : Wr;
        const float* p = Wsrc + f_a * 64 + (k8 & 63);
        float4 w0 = *(const float4*)p;
        float4 w1 = *(const float4*)(p + 4);
        float w[8] = {w0.x, w0.y, w0.z, w0.w, w1.x, w1.y, w1.z, w1.w};
        bf16x8 h, l;
#pragma unroll
        for (int jj = 0; jj < 8; ++jj) {
            unsigned int hb = f2bf_rne(w[jj]);
            float hf = __uint_as_float(hb << 16);
            unsigned int lb = f2bf_rne(w[jj] - hf);
            h[jj] = (short)hb;
            l[jj] = (short)lb;
        }
        wh[s] = h;
        wlo[s] = l;
    }

    __syncthreads();

    // ---- phase C: MFMA, out[f][node] tiles; K = [mean(64) ; x(64)] ----
    f32x4 acc[4];
#pragma unroll
    for (int nt = 0; nt < 4; ++nt) acc[nt] = (f32x4){0.f, 0.f, 0.f, 0.f};

#pragma unroll
    for (int nt = 0; nt < 4; ++nt) {
        int nl = nt * 16 + lm;
        int node = node0 + nl;
        bool v = node < N;
        const unsigned int* xrow = xin + (long long)node * 32;
#pragma unroll
        for (int s = 0; s < 2; ++s) {            // mean fragments from LDS
            union { uint4 u4; bf16x8 v8; } cv;
            cv.u4 = smean[nl][(s * 4 + quad) ^ (lm & 7)];
            acc[nt] = __builtin_amdgcn_mfma_f32_16x16x32_bf16(wh[s],  cv.v8, acc[nt], 0, 0, 0);
            acc[nt] = __builtin_amdgcn_mfma_f32_16x16x32_bf16(wlo[s], cv.v8, acc[nt], 0, 0, 0);
        }
#pragma unroll
        for (int s = 2; s < 4; ++s) {            // self fragments from global
            uint4 u = make_uint4(0u, 0u, 0u, 0u);
            if (v) u = *(const uint4*)(xrow + ((s & 1) << 4) + (quad << 2));
            union { uint4 u4; bf16x8 v8; } cv;
            cv.u4 = u;
            acc[nt] = __builtin_amdgcn_mfma_f32_16x16x32_bf16(wh[s],  cv.v8, acc[nt], 0, 0, 0);
            acc[nt] = __builtin_amdgcn_mfma_f32_16x16x32_bf16(wlo[s], cv.v8, acc[nt], 0, 0, 0);
        }
    }

    int fb = (wave << 4) + quad * 4;
    float4 bv = *(const float4*)(bias + fb);
#pragma unroll
    for (int nt = 0; nt < 4; ++nt) {
        int node = node0 + nt * 16 + lm;
        if (node >= N) continue;
        float r0 = acc[nt][0] + bv.x;
        float r1 = acc[nt][1] + bv.y;
        float r2 = acc[nt][2] + bv.z;
        float r3 = acc[nt][3] + bv.w;
        if (relu) {
            r0 = fmaxf(r0, 0.f); r1 = fmaxf(r1, 0.f);
            r2 = fmaxf(r2, 0.f); r3 = fmaxf(r3, 0.f);
        }
        if (outf) *(float4*)(outf + (long long)node * D + fb) = make_float4(r0, r1, r2, r3);
        if (outb) *(uint2*)(outb + (long long)node * 32 + (fb >> 1)) =
                      make_uint2(pack_bf(r0, r1), pack_bf(r2, r3));
    }
}

extern "C" void kernel_launch(void* const* d_in, const int* in_sizes, int n_in,
                              void* d_out, int out_size, void* d_ws, size_t ws_size,
                              hipStream_t stream) {
    const float* x   = (const float*)d_in[0];
    const int* ei    = (const int*)d_in[1];
    const float* W1l = (const float*)d_in[2];
    const float* W1r = (const float*)d_in[3];
    const float* b1  = (const float*)d_in[4];
    const float* W2l = (const float*)d_in[5];
    const float* W2r = (const float*)d_in[6];
    const float* b2  = (const float*)d_in[7];

    const int E = in_sizes[1] / 2;
    const int N = in_sizes[0] / D;     // requires N <= 131072 (17-bit packing)
    const int* src  = ei;
    const int* dstp = ei + E;
    const int NR  = (N + RN - 1) >> RSH;          // 196 for N=100k
    const int NBF = (N + BN2 - 1) >> BSH2;        // 1563 fine buckets / fused tiles
    const int G1 = 512;                           // latency hiding for the coarse scatter
    const int CE = (E + G1 - 1) / G1;

    char* ws = (char*)d_ws;
    size_t off = 0;
    auto alloc = [&](size_t bytes) { void* p = ws + off; off = (off + bytes + 255) & ~(size_t)255; return p; };
    int* cnt             = (int*)alloc((size_t)NR * 4);
    int* cnt2            = (int*)alloc((size_t)(NR * 8) * 4);
    unsigned int* pairs  = (unsigned int*)alloc(((size_t)(NR + 1) << RCAPSH) * 4);   // ~12.9MB
    unsigned int* pairs2 = (unsigned int*)alloc(((size_t)(NR * 8 + 8) << FCAPSH) * 4); // ~12.9MB
    unsigned int* xb     = (unsigned int*)alloc((size_t)N * 32 * 4);  // bf16 x
    unsigned int* hb     = (unsigned int*)alloc((size_t)N * 32 * 4);  // bf16 h

    float* out = (float*)d_out;

    // ---- cast features to bf16 (+ zero coarse region counters) ----
    cast_kernel<<<2048, 256, 0, stream>>>((const float4*)x, (uint2*)xb, N * 16, cnt, NR);

    // ---- level 1: coarse 512-node-region scatter ----
    binscatter_kernel<<<G1, 256, 0, stream>>>(src, dstp, cnt, pairs, E, NR, CE);

    // ---- level 2: rebin regions 8-way into fine 64-node buckets (coalesced, no atomics) ----
    rebin_kernel<<<NR, 256, 0, stream>>>(pairs, cnt, pairs2, cnt2, NR);

    // ---- layer 1: sort + gather-mean + MFMA linear -> bf16 h ----
    fused_layer_kernel<<<NBF, 256, 0, stream>>>(xb, pairs2, cnt2, W1l, W1r, b1,
                                                nullptr, hb, N, 1);
    // ---- layer 2: sort + gather-mean + MFMA linear -> fp32 out ----
    fused_layer_kernel<<<NBF, 256, 0, stream>>>(hb, pairs2, cnt2, W2l, W2r, b2,
                                                out, nullptr, N, 0);
}

// Round 12
// 216.589 us; speedup vs baseline: 1.1618x; 1.0782x over previous
//
#include <hip/hip_runtime.h>

#define D 64
#define BSH2 6                // 64 nodes per bucket == one fused-layer tile
#define BN2 (1 << BSH2)
#define NBK_MAX 2048          // supports N up to 131072
#define CAP2SH 11             // 2048-record capacity per bucket region (mean 1024, +32 sigma)
#define CAP2 (1 << CAP2SH)
#define SIDX_MAX (CAP2 + 3 * BN2)   // sorted-index LDS incl. per-node 4-align padding

typedef __attribute__((ext_vector_type(8))) short bf16x8;
typedef __attribute__((ext_vector_type(4))) float f32x4;

// ---------- bf16 helpers (bit-exact RNE pack, shift-based unpack) ----------
__device__ __forceinline__ unsigned int f2bf_rne(float f) {
    unsigned int b = __float_as_uint(f);
    return (b + 0x7fffu + ((b >> 16) & 1u)) >> 16;
}
__device__ __forceinline__ unsigned int pack_bf(float lo, float hi) {
    return f2bf_rne(lo) | (f2bf_rne(hi) << 16);
}
__device__ __forceinline__ float bflo(unsigned int u) { return __uint_as_float(u << 16); }
__device__ __forceinline__ float bfhi(unsigned int u) { return __uint_as_float(u & 0xffff0000u); }

// ---------- merged cast + bucket scatter ----------
// Blocks [0,GS): single-pass scatter of (src | dst_low<<17) into CAP2-strided bucket
// regions (bucket = 64 dst nodes = one fused tile). Per-block LDS histogram, ONE global
// atomicAdd per (block,bucket) to reserve a run, then dense scatter. GS=256 (was 512 in
// R9): 4-record (16B) runs per (block,bucket) halve the per-64B-line XCD contention that
// caused R9's 48MB write amplification at 1.1 TB/s effective.
// Blocks [GS,GS+GC): cast fp32 features -> packed bf16 (HBM-BW-bound; co-schedules with
// the latency-bound scatter on disjoint resources).
// cnt[] must be zeroed beforehand (hipMemsetAsync on the stream).
__global__ __launch_bounds__(256) void cast_scatter_kernel(
    const float4* __restrict__ xin, uint2* __restrict__ xb, int n4,
    const int* __restrict__ src, const int* __restrict__ dst,
    int* __restrict__ cnt, unsigned int* __restrict__ pairs,
    int E, int NBK, int CE, int GS) {
    __shared__ int lh[NBK_MAX];
    __shared__ int lbase[NBK_MAX];
    int b = blockIdx.x;
    if (b >= GS) {
        // ---- cast role ----
        int gid = (b - GS) * 256 + threadIdx.x;
        int stride = (gridDim.x - GS) * 256;
        for (int i = gid; i < n4; i += stride) {
            float4 v = xin[i];
            uint2 o;
            o.x = pack_bf(v.x, v.y);
            o.y = pack_bf(v.z, v.w);
            xb[i] = o;
        }
        return;
    }
    // ---- scatter role ----
    for (int k = threadIdx.x; k < NBK; k += 256) lh[k] = 0;
    __syncthreads();
    int beg = b * CE, end = min(beg + CE, E);
    for (int e = beg + threadIdx.x; e < end; e += 256)
        atomicAdd(&lh[dst[e] >> BSH2], 1);
    __syncthreads();
    for (int k = threadIdx.x; k < NBK; k += 256) {
        int c = lh[k];
        if (c) lbase[k] = (k << CAP2SH) + atomicAdd(&cnt[k], c);
        lh[k] = 0;
    }
    __syncthreads();
    for (int e = beg + threadIdx.x; e < end; e += 256) {
        int d = dst[e];
        int k = d >> BSH2;
        int r = atomicAdd(&lh[k], 1);
        pairs[lbase[k] + r] = (unsigned int)src[e] | ((unsigned int)(d & (BN2 - 1)) << 17);
    }
}

// ---------- fused layer (R9 champion): in-LDS counting sort + gather-mean + MFMA ----------
// One block (256 thr = 4 waves) per 64-node bucket. Phase A: stage this bucket's ~1024
// unsorted records into LDS (one coalesced read), 64-counter hist, 64-wide padded scan
// (node bases 4-aligned), LDS scatter -> per-node contiguous index lists in sidx.
// Phase B: register gather (wave w: nodes [w*16,w*16+16) in two octets, 8 lanes x
// uint4/row, 4-deep unroll), index int4 via ds_read_b128. Means -> swizzled bf16 LDS
// tile (overlays the dead record stage). Phase C: 16x16x32 MFMA with hi/lo-split
// weights (fp32-accurate).
__global__ __launch_bounds__(256) void fused_layer_kernel(
    const unsigned int* __restrict__ xin, const unsigned int* __restrict__ pairs,
    const int* __restrict__ cnt,
    const float* __restrict__ Wl, const float* __restrict__ Wr,
    const float* __restrict__ bias,
    float* __restrict__ outf, unsigned int* __restrict__ outb, int N, int relu) {
    __shared__ uint4 smean[BN2][8];     // 8KB; overlaid as the raw record stage in phase A
    __shared__ int sidx[SIDX_MAX];      // sorted src indices, per-node 4-aligned lists
    __shared__ int lcnt[BN2];           // true degree
    __shared__ int lbase[BN2];          // 4-aligned list base
    __shared__ int lcur[BN2];           // scatter cursor
    __shared__ int sscan[BN2];

    unsigned int* spr = (unsigned int*)&smean[0][0];   // phase-A overlay (2048 uints)

    int tid = threadIdx.x;
    int wave = tid >> 6;
    int lane = tid & 63;
    int b = blockIdx.x;
    int node0 = b << BSH2;

    // ---- phase A: stage + counting sort in LDS ----
    int cntk = min(cnt[b], CAP2);
    if (tid < BN2) lcnt[tid] = 0;
    __syncthreads();
    int rbeg = b << CAP2SH;
    for (int i = tid; i < cntk; i += 256) {
        unsigned int rec = pairs[rbeg + i];
        spr[i] = rec;
        atomicAdd(&lcnt[rec >> 17], 1);
    }
    __syncthreads();
    int deg = (tid < BN2) ? lcnt[tid] : 0;
    int ps  = (deg + 3) & ~3;           // pad each node's list to 4-record alignment
    if (tid < BN2) sscan[tid] = ps;
    __syncthreads();
    for (int off = 1; off < BN2; off <<= 1) {
        int t = (tid < BN2 && tid >= off) ? sscan[tid - off] : 0;
        __syncthreads();
        if (tid < BN2) sscan[tid] += t;
        __syncthreads();
    }
    if (tid < BN2) {
        int base = sscan[tid] - ps;     // exclusive prefix of padded degrees, 4-aligned
        lbase[tid] = base;
        lcur[tid] = base;
    }
    __syncthreads();
    for (int i = tid; i < cntk; i += 256) {
        unsigned int rec = spr[i];
        int j = rec >> 17;
        int pos = atomicAdd(&lcur[j], 1);
        sidx[pos] = (int)(rec & 0x1FFFFu);
    }
    __syncthreads();                    // spr dead from here; smean reuses the space

    // ---- phase B: aggregation (register accumulation, indices from LDS) ----
    int q  = lane >> 3;                 // node within octet
    int fl = lane & 7;                  // uint4 granule within 128B row
    for (int o = 0; o < 2; ++o) {
        int nl = (wave << 4) + (o << 3) + q;      // local node 0..63
        int beg = lbase[nl];
        int dg  = lcnt[nl];
        int end = beg + dg;
        float s0 = 0.f, s1 = 0.f, s2 = 0.f, s3 = 0.f;
        float s4 = 0.f, s5 = 0.f, s6 = 0.f, s7 = 0.f;
        int j = beg;
        for (; j + 4 <= end; j += 4) {
            int4 iv = *(const int4*)(sidx + j);   // 16B-aligned ds_read_b128
            uint4 u0 = *(const uint4*)(xin + iv.x * 32 + fl * 4);
            uint4 u1 = *(const uint4*)(xin + iv.y * 32 + fl * 4);
            uint4 u2 = *(const uint4*)(xin + iv.z * 32 + fl * 4);
            uint4 u3 = *(const uint4*)(xin + iv.w * 32 + fl * 4);
            s0 += bflo(u0.x) + bflo(u1.x) + bflo(u2.x) + bflo(u3.x);
            s1 += bfhi(u0.x) + bfhi(u1.x) + bfhi(u2.x) + bfhi(u3.x);
            s2 += bflo(u0.y) + bflo(u1.y) + bflo(u2.y) + bflo(u3.y);
            s3 += bfhi(u0.y) + bfhi(u1.y) + bfhi(u2.y) + bfhi(u3.y);
            s4 += bflo(u0.z) + bflo(u1.z) + bflo(u2.z) + bflo(u3.z);
            s5 += bfhi(u0.z) + bfhi(u1.z) + bfhi(u2.z) + bfhi(u3.z);
            s6 += bflo(u0.w) + bflo(u1.w) + bflo(u2.w) + bflo(u3.w);
            s7 += bfhi(u0.w) + bfhi(u1.w) + bfhi(u2.w) + bfhi(u3.w);
        }
        for (; j < end; ++j) {
            uint4 u = *(const uint4*)(xin + sidx[j] * 32 + fl * 4);
            s0 += bflo(u.x); s1 += bfhi(u.x);
            s2 += bflo(u.y); s3 += bfhi(u.y);
            s4 += bflo(u.z); s5 += bfhi(u.z);
            s6 += bflo(u.w); s7 += bfhi(u.w);
        }
        float inv = 1.0f / fmaxf((float)dg, 1.0f);
        uint4 ov;
        ov.x = pack_bf(s0 * inv, s1 * inv);
        ov.y = pack_bf(s2 * inv, s3 * inv);
        ov.z = pack_bf(s4 * inv, s5 * inv);
        ov.w = pack_bf(s6 * inv, s7 * inv);
        smean[nl][fl ^ (nl & 7)] = ov;   // zero-degree nodes write zeros (dg=0 -> sums 0)
    }

    // ---- weight fragments (overlap load latency with barrier wait) ----
    int lm   = lane & 15;
    int quad = lane >> 4;
    int f_a  = (wave << 4) + lm;
    bf16x8 wh[4], wlo[4];
#pragma unroll
    for (int s = 0; s < 4; ++s) {
        int k8 = s * 32 + quad * 8;
        const float* Wsrc = (k8 < 64) ? Wl : Wr;
        const float* p = Wsrc + f_a * 64 + (k8 & 63);
        float4 w0 = *(const float4*)p;
        float4 w1 = *(const float4*)(p + 4);
        float w[8] = {w0.x, w0.y, w0.z, w0.w, w1.x, w1.y, w1.z, w1.w};
        bf16x8 h, l;
#pragma unroll
        for (int jj = 0; jj < 8; ++jj) {
            unsigned int hb = f2bf_rne(w[jj]);
            float hf = __uint_as_float(hb << 16);
            unsigned int lb = f2bf_rne(w[jj] - hf);
            h[jj] = (short)hb;
            l[jj] = (short)lb;
        }
        wh[s] = h;
        wlo[s] = l;
    }

    __syncthreads();

    // ---- phase C: MFMA, out[f][node] tiles; K = [mean(64) ; x(64)] ----
    f32x4 acc[4];
#pragma unroll
    for (int nt = 0; nt < 4; ++nt) acc[nt] = (f32x4){0.f, 0.f, 0.f, 0.f};

#pragma unroll
    for (int nt = 0; nt < 4; ++nt) {
        int nl = nt * 16 + lm;
        int node = node0 + nl;
        bool v = node < N;
        const unsigned int* xrow = xin + (long long)node * 32;
#pragma unroll
        for (int s = 0; s < 2; ++s) {            // mean fragments from LDS
            union { uint4 u4; bf16x8 v8; } cv;
            cv.u4 = smean[nl][(s * 4 + quad) ^ (lm & 7)];
            acc[nt] = __builtin_amdgcn_mfma_f32_16x16x32_bf16(wh[s],  cv.v8, acc[nt], 0, 0, 0);
            acc[nt] = __builtin_amdgcn_mfma_f32_16x16x32_bf16(wlo[s], cv.v8, acc[nt], 0, 0, 0);
        }
#pragma unroll
        for (int s = 2; s < 4; ++s) {            // self fragments from global
            uint4 u = make_uint4(0u, 0u, 0u, 0u);
            if (v) u = *(const uint4*)(xrow + ((s & 1) << 4) + (quad << 2));
            union { uint4 u4; bf16x8 v8; } cv;
            cv.u4 = u;
            acc[nt] = __builtin_amdgcn_mfma_f32_16x16x32_bf16(wh[s],  cv.v8, acc[nt], 0, 0, 0);
            acc[nt] = __builtin_amdgcn_mfma_f32_16x16x32_bf16(wlo[s], cv.v8, acc[nt], 0, 0, 0);
        }
    }

    int fb = (wave << 4) + quad * 4;
    float4 bv = *(const float4*)(bias + fb);
#pragma unroll
    for (int nt = 0; nt < 4; ++nt) {
        int node = node0 + nt * 16 + lm;
        if (node >= N) continue;
        float r0 = acc[nt][0] + bv.x;
        float r1 = acc[nt][1] + bv.y;
        float r2 = acc[nt][2] + bv.z;
        float r3 = acc[nt][3] + bv.w;
        if (relu) {
            r0 = fmaxf(r0, 0.f); r1 = fmaxf(r1, 0.f);
            r2 = fmaxf(r2, 0.f); r3 = fmaxf(r3, 0.f);
        }
        if (outf) *(float4*)(outf + (long long)node * D + fb) = make_float4(r0, r1, r2, r3);
        if (outb) *(uint2*)(outb + (long long)node * 32 + (fb >> 1)) =
                      make_uint2(pack_bf(r0, r1), pack_bf(r2, r3));
    }
}

extern "C" void kernel_launch(void* const* d_in, const int* in_sizes, int n_in,
                              void* d_out, int out_size, void* d_ws, size_t ws_size,
                              hipStream_t stream) {
    const float* x   = (const float*)d_in[0];
    const int* ei    = (const int*)d_in[1];
    const float* W1l = (const float*)d_in[2];
    const float* W1r = (const float*)d_in[3];
    const float* b1  = (const float*)d_in[4];
    const float* W2l = (const float*)d_in[5];
    const float* W2r = (const float*)d_in[6];
    const float* b2  = (const float*)d_in[7];

    const int E = in_sizes[1] / 2;
    const int N = in_sizes[0] / D;     // requires N <= 131072 (17-bit packing)
    const int* src  = ei;
    const int* dstp = ei + E;
    const int NBK = (N + BN2 - 1) >> BSH2;        // 1563 for N=100k
    const int GS = 256;                           // scatter blocks: 4-record (16B) runs
    const int GC = 256;                           // cast blocks
    const int CE = (E + GS - 1) / GS;

    char* ws = (char*)d_ws;
    size_t off = 0;
    auto alloc = [&](size_t bytes) { void* p = ws + off; off = (off + bytes + 255) & ~(size_t)255; return p; };
    int* cnt            = (int*)alloc((size_t)NBK * 4);
    unsigned int* pairs = (unsigned int*)alloc(((size_t)(NBK + 1) << CAP2SH) * 4);  // +1 region overflow guard
    unsigned int* xb    = (unsigned int*)alloc((size_t)N * 32 * 4);  // bf16 x
    unsigned int* hb    = (unsigned int*)alloc((size_t)N * 32 * 4);  // bf16 h

    float* out = (float*)d_out;

    // ---- zero bucket counters (stream-ordered, capture-safe) ----
    hipMemsetAsync(cnt, 0, (size_t)NBK * 4, stream);

    // ---- merged: cast features to bf16 || 64-node-bucket scatter ----
    cast_scatter_kernel<<<GS + GC, 256, 0, stream>>>((const float4*)x, (uint2*)xb, N * 16,
                                                     src, dstp, cnt, pairs, E, NBK, CE, GS);

    // ---- layer 1: sort + gather-mean + MFMA linear -> bf16 h ----
    fused_layer_kernel<<<NBK, 256, 0, stream>>>(xb, pairs, cnt, W1l, W1r, b1,
                                                nullptr, hb, N, 1);
    // ---- layer 2: sort + gather-mean + MFMA linear -> fp32 out ----
    fused_layer_kernel<<<NBK, 256, 0, stream>>>(hb, pairs, cnt, W2l, W2r, b2,
                                                out, nullptr, N, 0);
}